// Round 1
// baseline (325.214 us; speedup 1.0000x reference)
//
#include <hip/hip_runtime.h>
#include <hip/hip_bf16.h>
#include <cstdint>
#include <cstddef>

typedef __bf16 bf16;
typedef bf16 bf16x4 __attribute__((ext_vector_type(4)));
typedef bf16 bf16x8 __attribute__((ext_vector_type(8)));
typedef float f32x4 __attribute__((ext_vector_type(4)));

#define SEQ 2048
#define EMB 1024
#define NH 16
#define HD 64
#define BSZ 2
#define MROWS (BSZ*SEQ)   // 4096

__device__ __forceinline__ void gload_lds16(const void* g, void* lds) {
  __builtin_amdgcn_global_load_lds((__attribute__((address_space(1))) void*)g,
                                   (__attribute__((address_space(3))) void*)lds,
                                   16, 0, 0);
}

// ---------------- f32 -> bf16 convert (vectorized) ----------------
__global__ void cvt_kernel(const float* __restrict__ src, bf16* __restrict__ dst, int n4) {
  int i = blockIdx.x * blockDim.x + threadIdx.x;
  if (i >= n4) return;
  const float4 v = reinterpret_cast<const float4*>(src)[i];
  bf16x4 o;
  o[0] = (bf16)v.x; o[1] = (bf16)v.y; o[2] = (bf16)v.z; o[3] = (bf16)v.w;
  reinterpret_cast<bf16x4*>(dst)[i] = o;
}

// ---------------- RoPE tables ----------------
__global__ void rope_tables_kernel(float* __restrict__ cosT, float* __restrict__ sinT) {
  int idx = blockIdx.x * blockDim.x + threadIdx.x; // s*32 + j
  if (idx >= SEQ * 32) return;
  int s = idx >> 5, j = idx & 31;
  float ex = (2.0f * (float)j) / 64.0f;
  float inv = 1.0f / powf(10000.0f, ex);
  float ang = (float)s * inv;
  cosT[idx] = cosf(ang);
  sinT[idx] = sinf(ang);
}

// ---------------- RoPE apply (in place on bf16 q,k in (B,H,S,D)) ----------------
__global__ void rope_apply_kernel(bf16* __restrict__ qb, bf16* __restrict__ kb,
                                  const float* __restrict__ cosT, const float* __restrict__ sinT) {
  int idx = blockIdx.x * blockDim.x + threadIdx.x; // over BSZ*NH*SEQ*32 pairs
  if (idx >= BSZ * NH * SEQ * 32) return;
  int j = idx & 31;
  int s = (idx >> 5) & (SEQ - 1);
  int bh = idx >> 16;                       // SEQ*32 = 65536 per (b,h)
  float c = cosT[(s << 5) + j], sn = sinT[(s << 5) + j];
  size_t base = ((size_t)bh * SEQ + s) * HD + 2 * j;
  float q0 = (float)qb[base], q1 = (float)qb[base + 1];
  qb[base]     = (bf16)(q0 * c - q1 * sn);
  qb[base + 1] = (bf16)(q0 * sn + q1 * c);
  float k0 = (float)kb[base], k1 = (float)kb[base + 1];
  kb[base]     = (bf16)(k0 * c - k1 * sn);
  kb[base + 1] = (bf16)(k0 * sn + k1 * c);
}

// ---------------- GEMM C = A @ B^T (+bias), 128x128 tile, bf16 MFMA ----------------
// A: (M,K) bf16 row-major. B: (N,K) bf16 row-major. EPI=0: f32 out. EPI=1: qkv scatter.
template<int EPI>
__launch_bounds__(256)
__global__ void gemm_bt(const bf16* __restrict__ A, const bf16* __restrict__ B,
                        const float* __restrict__ bias,
                        float* __restrict__ Cf,
                        bf16* __restrict__ qb, bf16* __restrict__ kb, bf16* __restrict__ vt,
                        int Ndim, int Kdim) {
  __shared__ __align__(16) bf16 Alds[128 * 32];
  __shared__ __align__(16) bf16 Blds[128 * 32];
  const int tid = threadIdx.x;
  const int wave = tid >> 6, lane = tid & 63;
  const int wr = wave >> 1, wc = wave & 1;
  const int bm = blockIdx.x * 128, bn = blockIdx.y * 128;

  f32x4 acc[4][4] = {};

  const int srow = lane >> 2;        // 0..15 within 16-row chunk
  const int scol = (lane & 3) * 8;   // element col within 32-wide tile
  char* aldsb = (char*)Alds;
  char* bldsb = (char*)Blds;

  for (int kt = 0; kt < Kdim; kt += 32) {
    gload_lds16(A + (size_t)(bm + wave * 16 + srow) * Kdim + kt + scol, aldsb + wave * 1024);
    gload_lds16(A + (size_t)(bm + (wave + 4) * 16 + srow) * Kdim + kt + scol, aldsb + wave * 1024 + 4096);
    gload_lds16(B + (size_t)(bn + wave * 16 + srow) * Kdim + kt + scol, bldsb + wave * 1024);
    gload_lds16(B + (size_t)(bn + (wave + 4) * 16 + srow) * Kdim + kt + scol, bldsb + wave * 1024 + 4096);
    __syncthreads();
    bf16x8 af[4], bfr[4];
#pragma unroll
    for (int m = 0; m < 4; m++)
      af[m] = *reinterpret_cast<const bf16x8*>(Alds + (wr * 64 + m * 16 + (lane & 15)) * 32 + (lane >> 4) * 8);
#pragma unroll
    for (int n = 0; n < 4; n++)
      bfr[n] = *reinterpret_cast<const bf16x8*>(Blds + (wc * 64 + n * 16 + (lane & 15)) * 32 + (lane >> 4) * 8);
#pragma unroll
    for (int m = 0; m < 4; m++)
#pragma unroll
      for (int n = 0; n < 4; n++)
        acc[m][n] = __builtin_amdgcn_mfma_f32_16x16x32_bf16(af[m], bfr[n], acc[m][n], 0, 0, 0);
    __syncthreads();
  }

#pragma unroll
  for (int m = 0; m < 4; m++) {
#pragma unroll
    for (int n = 0; n < 4; n++) {
#pragma unroll
      for (int r = 0; r < 4; r++) {
        const int row = bm + wr * 64 + m * 16 + (lane >> 4) * 4 + r;
        const int col = bn + wc * 64 + n * 16 + (lane & 15);
        const float v = acc[m][n][r] + bias[col];
        if (EPI == 0) {
          Cf[(size_t)row * Ndim + col] = v;
        } else {
          const int b = row >> 11, s = row & (SEQ - 1);
          const int which = col >> 10, rem = col & 1023;
          const int h = rem >> 6, d = rem & 63;
          const bf16 bv = (bf16)v;
          if (which == 0)      qb[(((size_t)(b * NH + h) * SEQ) + s) * HD + d] = bv;
          else if (which == 1) kb[(((size_t)(b * NH + h) * SEQ) + s) * HD + d] = bv;
          else                 vt[(((size_t)(b * NH + h) * HD) + d) * SEQ + s] = bv;  // V transposed
        }
      }
    }
  }
}

// ---------------- Flash attention: 4 waves, 64 q-rows/block, KVBLK=64 ----------------
__launch_bounds__(256)
__global__ void attn_kernel(const bf16* __restrict__ qb, const bf16* __restrict__ kb,
                            const bf16* __restrict__ vt, bf16* __restrict__ ob) {
  const int bidx = blockIdx.x;
  const int qblk = bidx & 31;         // S/64 = 32
  const int bh = bidx >> 5;           // 0..31 (consecutive blocks share K/V in L2)
  const int b = bh >> 4, h = bh & 15;
  const int tid = threadIdx.x;
  const int wave = tid >> 6, lane = tid & 63;
  const int q0 = qblk * 64 + wave * 16;

  __shared__ __align__(16) bf16 Plds[4][16][72];  // +8 pad: breaks bank conflicts

  const bf16* Qb = qb + (size_t)bh * SEQ * HD;
  const bf16* Kb = kb + (size_t)bh * SEQ * HD;
  const bf16* Vb = vt + (size_t)bh * HD * SEQ;

  bf16x8 qa[2];
#pragma unroll
  for (int c = 0; c < 2; c++)
    qa[c] = *reinterpret_cast<const bf16x8*>(Qb + (size_t)(q0 + (lane & 15)) * HD + c * 32 + (lane >> 4) * 8);

  f32x4 oacc[4] = {};
  float mrun[4], lrun[4];
#pragma unroll
  for (int r = 0; r < 4; r++) { mrun[r] = -1e30f; lrun[r] = 0.f; }

  for (int kv0 = 0; kv0 < SEQ; kv0 += 64) {
    f32x4 sfr[4];
#pragma unroll
    for (int nf = 0; nf < 4; nf++) {
      f32x4 s = {};
#pragma unroll
      for (int c = 0; c < 2; c++) {
        const bf16x8 kf = *reinterpret_cast<const bf16x8*>(
            Kb + (size_t)(kv0 + nf * 16 + (lane & 15)) * HD + c * 32 + (lane >> 4) * 8);
        s = __builtin_amdgcn_mfma_f32_16x16x32_bf16(qa[c], kf, s, 0, 0, 0);
      }
      sfr[nf] = s * 0.125f;  // 1/sqrt(64)
    }
    // online softmax: rows live in 16-lane col-groups -> shfl_xor reduce over low 4 bits
#pragma unroll
    for (int r = 0; r < 4; r++) {
      float x = fmaxf(fmaxf(sfr[0][r], sfr[1][r]), fmaxf(sfr[2][r], sfr[3][r]));
      x = fmaxf(x, __shfl_xor(x, 1, 64));
      x = fmaxf(x, __shfl_xor(x, 2, 64));
      x = fmaxf(x, __shfl_xor(x, 4, 64));
      x = fmaxf(x, __shfl_xor(x, 8, 64));
      const float mnew = fmaxf(mrun[r], x);
      const float alpha = __expf(mrun[r] - mnew);
      mrun[r] = mnew;
      float rsum = 0.f;
#pragma unroll
      for (int nf = 0; nf < 4; nf++) {
        const float pv = __expf(sfr[nf][r] - mnew);
        sfr[nf][r] = pv;
        rsum += pv;
      }
      rsum += __shfl_xor(rsum, 1, 64);
      rsum += __shfl_xor(rsum, 2, 64);
      rsum += __shfl_xor(rsum, 4, 64);
      rsum += __shfl_xor(rsum, 8, 64);
      lrun[r] = lrun[r] * alpha + rsum;
#pragma unroll
      for (int nf = 0; nf < 4; nf++) oacc[nf][r] *= alpha;
    }
    // P (C-layout) -> LDS -> A-frag layout
    __syncthreads();
#pragma unroll
    for (int nf = 0; nf < 4; nf++)
#pragma unroll
      for (int r = 0; r < 4; r++)
        Plds[wave][(lane >> 4) * 4 + r][nf * 16 + (lane & 15)] = (bf16)sfr[nf][r];
    __syncthreads();
#pragma unroll
    for (int c = 0; c < 2; c++) {
      const bf16x8 pa = *reinterpret_cast<const bf16x8*>(&Plds[wave][lane & 15][c * 32 + (lane >> 4) * 8]);
#pragma unroll
      for (int nf = 0; nf < 4; nf++) {
        const bf16x8 vf = *reinterpret_cast<const bf16x8*>(
            Vb + (size_t)(nf * 16 + (lane & 15)) * SEQ + kv0 + c * 32 + (lane >> 4) * 8);
        oacc[nf] = __builtin_amdgcn_mfma_f32_16x16x32_bf16(pa, vf, oacc[nf], 0, 0, 0);
      }
    }
  }

#pragma unroll
  for (int nf = 0; nf < 4; nf++)
#pragma unroll
    for (int r = 0; r < 4; r++) {
      const int qrow = q0 + (lane >> 4) * 4 + r;
      const float v = oacc[nf][r] / lrun[r];
      ob[((size_t)b * SEQ + qrow) * EMB + h * HD + nf * 16 + (lane & 15)] = (bf16)v;
    }
}

extern "C" void kernel_launch(void* const* d_in, const int* in_sizes, int n_in,
                              void* d_out, int out_size, void* d_ws, size_t ws_size,
                              hipStream_t stream) {
  const float* x    = (const float*)d_in[0];   // query (reference only uses query)
  const float* Win  = (const float*)d_in[3];   // (3E, E)
  const float* bin  = (const float*)d_in[4];   // (3E,)
  const float* Wout = (const float*)d_in[5];   // (E, E)
  const float* bout = (const float*)d_in[6];   // (E,)
  float* out = (float*)d_out;

  char* p = (char*)d_ws;
  bf16* xb  = (bf16*)p; p += (size_t)MROWS * EMB * 2;       // 8 MB
  bf16* wb  = (bf16*)p; p += (size_t)3 * EMB * EMB * 2;     // 6 MB
  bf16* wob = (bf16*)p; p += (size_t)EMB * EMB * 2;         // 2 MB
  bf16* qb  = (bf16*)p; p += (size_t)MROWS * EMB * 2;       // 8 MB (B,H,S,D)
  bf16* kb  = (bf16*)p; p += (size_t)MROWS * EMB * 2;       // 8 MB (B,H,S,D)
  bf16* vt  = (bf16*)p; p += (size_t)MROWS * EMB * 2;       // 8 MB (B,H,D,S)
  bf16* ob  = (bf16*)p; p += (size_t)MROWS * EMB * 2;       // 8 MB (B,S,E)
  float* cosT = (float*)p; p += (size_t)SEQ * 32 * 4;
  float* sinT = (float*)p; p += (size_t)SEQ * 32 * 4;

  cvt_kernel<<<(MROWS * EMB / 4 + 255) / 256, 256, 0, stream>>>(x, xb, MROWS * EMB / 4);
  cvt_kernel<<<(3 * EMB * EMB / 4 + 255) / 256, 256, 0, stream>>>(Win, wb, 3 * EMB * EMB / 4);
  cvt_kernel<<<(EMB * EMB / 4 + 255) / 256, 256, 0, stream>>>(Wout, wob, EMB * EMB / 4);
  rope_tables_kernel<<<(SEQ * 32 + 255) / 256, 256, 0, stream>>>(cosT, sinT);

  gemm_bt<1><<<dim3(MROWS / 128, 3 * EMB / 128), 256, 0, stream>>>(
      xb, wb, bin, nullptr, qb, kb, vt, 3 * EMB, EMB);
  rope_apply_kernel<<<(BSZ * NH * SEQ * 32 + 255) / 256, 256, 0, stream>>>(qb, kb, cosT, sinT);
  attn_kernel<<<BSZ * NH * (SEQ / 64), 256, 0, stream>>>(qb, kb, vt, ob);
  gemm_bt<0><<<dim3(MROWS / 128, EMB / 128), 256, 0, stream>>>(
      ob, wob, bout, out, nullptr, nullptr, nullptr, EMB, EMB);
}

// Round 3
// 211.540 us; speedup vs baseline: 1.5374x; 1.5374x over previous
//
#include <hip/hip_runtime.h>
#include <hip/hip_bf16.h>
#include <cstdint>
#include <cstddef>

typedef __bf16 bf16;
typedef bf16 bf16x2 __attribute__((ext_vector_type(2)));
typedef bf16 bf16x4 __attribute__((ext_vector_type(4)));
typedef bf16 bf16x8 __attribute__((ext_vector_type(8)));
typedef float f32x4 __attribute__((ext_vector_type(4)));
typedef float f32x16 __attribute__((ext_vector_type(16)));

#define SEQ 2048
#define EMB 1024
#define NH 16
#define HD 64
#define BSZ 2
#define MROWS (BSZ*SEQ)   // 4096

__device__ __forceinline__ void gload_lds16(const void* g, void* lds) {
  __builtin_amdgcn_global_load_lds((__attribute__((address_space(1))) void*)g,
                                   (__attribute__((address_space(3))) void*)lds,
                                   16, 0, 0);
}

// ---------------- f32 -> bf16 convert (vectorized) ----------------
__global__ void cvt_kernel(const float* __restrict__ src, bf16* __restrict__ dst, int n4) {
  int i = blockIdx.x * blockDim.x + threadIdx.x;
  if (i >= n4) return;
  const float4 v = reinterpret_cast<const float4*>(src)[i];
  bf16x4 o;
  o[0] = (bf16)v.x; o[1] = (bf16)v.y; o[2] = (bf16)v.z; o[3] = (bf16)v.w;
  reinterpret_cast<bf16x4*>(dst)[i] = o;
}

// ---------------- RoPE tables ----------------
__global__ void rope_tables_kernel(float* __restrict__ cosT, float* __restrict__ sinT) {
  int idx = blockIdx.x * blockDim.x + threadIdx.x; // s*32 + j
  if (idx >= SEQ * 32) return;
  int s = idx >> 5, j = idx & 31;
  float ex = (2.0f * (float)j) / 64.0f;
  float inv = 1.0f / powf(10000.0f, ex);
  float ang = (float)s * inv;
  cosT[idx] = cosf(ang);
  sinT[idx] = sinf(ang);
}

// ---------------- RoPE apply (in place; q additionally scaled by 1/8) ----------------
__global__ void rope_apply_kernel(bf16* __restrict__ qb, bf16* __restrict__ kb,
                                  const float* __restrict__ cosT, const float* __restrict__ sinT) {
  int idx = blockIdx.x * blockDim.x + threadIdx.x; // over BSZ*NH*SEQ*32 pairs
  if (idx >= BSZ * NH * SEQ * 32) return;
  int j = idx & 31;
  int s = (idx >> 5) & (SEQ - 1);
  int bh = idx >> 16;                       // SEQ*32 = 65536 per (b,h)
  float c = cosT[(s << 5) + j], sn = sinT[(s << 5) + j];
  size_t base = ((size_t)bh * SEQ + s) * HD + 2 * j;
  float q0 = (float)qb[base], q1 = (float)qb[base + 1];
  // fold softmax scale 1/sqrt(64)=0.125 into q (exact: exponent shift)
  qb[base]     = (bf16)((q0 * c - q1 * sn) * 0.125f);
  qb[base + 1] = (bf16)((q0 * sn + q1 * c) * 0.125f);
  float k0 = (float)kb[base], k1 = (float)kb[base + 1];
  kb[base]     = (bf16)(k0 * c - k1 * sn);
  kb[base + 1] = (bf16)(k0 * sn + k1 * c);
}

// ---------------- GEMM C = A @ B^T (+bias), 128x128 tile, bf16 MFMA ----------------
// A: (M,K) bf16 row-major. B: (N,K) bf16 row-major. EPI=0: f32 out. EPI=1: qkv scatter.
template<int EPI>
__launch_bounds__(256)
__global__ void gemm_bt(const bf16* __restrict__ A, const bf16* __restrict__ B,
                        const float* __restrict__ bias,
                        float* __restrict__ Cf,
                        bf16* __restrict__ qb, bf16* __restrict__ kb, bf16* __restrict__ vt,
                        int Ndim, int Kdim) {
  __shared__ __align__(16) bf16 Alds[128 * 32];
  __shared__ __align__(16) bf16 Blds[128 * 32];
  const int tid = threadIdx.x;
  const int wave = tid >> 6, lane = tid & 63;
  const int wr = wave >> 1, wc = wave & 1;
  const int bm = blockIdx.x * 128, bn = blockIdx.y * 128;

  f32x4 acc[4][4] = {};

  const int srow = lane >> 2;        // 0..15 within 16-row chunk
  const int scol = (lane & 3) * 8;   // element col within 32-wide tile
  char* aldsb = (char*)Alds;
  char* bldsb = (char*)Blds;

  for (int kt = 0; kt < Kdim; kt += 32) {
    gload_lds16(A + (size_t)(bm + wave * 16 + srow) * Kdim + kt + scol, aldsb + wave * 1024);
    gload_lds16(A + (size_t)(bm + (wave + 4) * 16 + srow) * Kdim + kt + scol, aldsb + wave * 1024 + 4096);
    gload_lds16(B + (size_t)(bn + wave * 16 + srow) * Kdim + kt + scol, bldsb + wave * 1024);
    gload_lds16(B + (size_t)(bn + (wave + 4) * 16 + srow) * Kdim + kt + scol, bldsb + wave * 1024 + 4096);
    __syncthreads();
    bf16x8 af[4], bfr[4];
#pragma unroll
    for (int m = 0; m < 4; m++)
      af[m] = *reinterpret_cast<const bf16x8*>(Alds + (wr * 64 + m * 16 + (lane & 15)) * 32 + (lane >> 4) * 8);
#pragma unroll
    for (int n = 0; n < 4; n++)
      bfr[n] = *reinterpret_cast<const bf16x8*>(Blds + (wc * 64 + n * 16 + (lane & 15)) * 32 + (lane >> 4) * 8);
#pragma unroll
    for (int m = 0; m < 4; m++)
#pragma unroll
      for (int n = 0; n < 4; n++)
        acc[m][n] = __builtin_amdgcn_mfma_f32_16x16x32_bf16(af[m], bfr[n], acc[m][n], 0, 0, 0);
    __syncthreads();
  }

#pragma unroll
  for (int m = 0; m < 4; m++) {
#pragma unroll
    for (int n = 0; n < 4; n++) {
#pragma unroll
      for (int r = 0; r < 4; r++) {
        const int row = bm + wr * 64 + m * 16 + (lane >> 4) * 4 + r;
        const int col = bn + wc * 64 + n * 16 + (lane & 15);
        const float v = acc[m][n][r] + bias[col];
        if (EPI == 0) {
          Cf[(size_t)row * Ndim + col] = v;
        } else {
          const int b = row >> 11, s = row & (SEQ - 1);
          const int which = col >> 10, rem = col & 1023;
          const int h = rem >> 6, d = rem & 63;
          const bf16 bv = (bf16)v;
          if (which == 0)      qb[(((size_t)(b * NH + h) * SEQ) + s) * HD + d] = bv;
          else if (which == 1) kb[(((size_t)(b * NH + h) * SEQ) + s) * HD + d] = bv;
          else                 vt[(((size_t)(b * NH + h) * HD) + d) * SEQ + s] = bv;  // V transposed
        }
      }
    }
  }
}

// ---------------- Flash attention, swapped-QK^T 32x32, softmax fully in-register --------
// Per wave: 32 q-rows. S^T = mfma(A=K, B=Q^T): col = q = lane&31, row = k.
// Each lane owns one q-row; lanes l and l+32 hold disjoint k-halves.
// No LDS, no barriers. V consumed from vt (B,H,D,S) as A-operand of O^T = V^T @ P^T.
__device__ __forceinline__ unsigned pk2(float a, float b) {
  bf16x2 t; t[0] = (bf16)a; t[1] = (bf16)b;
  unsigned u; __builtin_memcpy(&u, &t, 4); return u;
}

__launch_bounds__(256)
__global__ void attn_kernel(const bf16* __restrict__ qb, const bf16* __restrict__ kb,
                            const bf16* __restrict__ vt, bf16* __restrict__ ob) {
  const int bidx = blockIdx.x;
  const int qblk = bidx & 15;         // 16 blocks of 128 q-rows per (b,h)
  const int bh = bidx >> 4;           // consecutive blocks share K/V in L2
  const int b = bh >> 4, h = bh & 15;
  const int wave = threadIdx.x >> 6, lane = threadIdx.x & 63;
  const int q0 = qblk * 128 + wave * 32;
  const int ql = lane & 31, hi = lane >> 5;

  const bf16* Qb = qb + (size_t)bh * SEQ * HD;
  const bf16* Kb = kb + (size_t)bh * SEQ * HD;
  const bf16* Vb = vt + (size_t)bh * HD * SEQ;

  // Q fragments (B-operand): lane holds col q=ql, d = dk*16 + hi*8 + j
  bf16x8 qf[4];
#pragma unroll
  for (int dk = 0; dk < 4; dk++)
    qf[dk] = *reinterpret_cast<const bf16x8*>(Qb + (size_t)(q0 + ql) * HD + dk * 16 + hi * 8);

  f32x16 oacc0 = {}, oacc1 = {};   // O^T d-tiles [0,32) and [32,64)
  float mrun = -1e30f, lrun = 0.f;

  for (int kv0 = 0; kv0 < SEQ; kv0 += 32) {
    // S^T tile: A = K rows (k = kv0+ql), B = Q^T
    f32x16 s = {};
#pragma unroll
    for (int dk = 0; dk < 4; dk++) {
      const bf16x8 kf = *reinterpret_cast<const bf16x8*>(
          Kb + (size_t)(kv0 + ql) * HD + dk * 16 + hi * 8);
      s = __builtin_amdgcn_mfma_f32_32x32x16_bf16(kf, qf[dk], s, 0, 0, 0);
    }
    // lane holds 16 scores of q-row ql: k = (r&3) + 8*(r>>2) + 4*hi
    float mx = s[0];
#pragma unroll
    for (int r = 1; r < 16; r++) mx = fmaxf(mx, s[r]);
    mx = fmaxf(mx, __shfl_xor(mx, 32, 64));
    const float mnew = fmaxf(mrun, mx);
    const float alpha = __expf(mrun - mnew);
    float p[16];
    float rsum = 0.f;
#pragma unroll
    for (int r = 0; r < 16; r++) { p[r] = __expf(s[r] - mnew); rsum += p[r]; }
    rsum += __shfl_xor(rsum, 32, 64);
    mrun = mnew;
    lrun = lrun * alpha + rsum;
#pragma unroll
    for (int r = 0; r < 16; r++) { oacc0[r] *= alpha; oacc1[r] *= alpha; }

    // pack P to bf16 pairs and exchange halves -> B-frag (P^T) for PV.
    // CONVERGENT exchange: select the word the partner needs (data select),
    // one unconditional shfl_xor(32) per word, then data-select into place.
    const unsigned a0 = pk2(p[0], p[1]),  a1 = pk2(p[2], p[3]);
    const unsigned a2 = pk2(p[4], p[5]),  a3 = pk2(p[6], p[7]);
    const unsigned b0 = pk2(p[8], p[9]),  b1 = pk2(p[10], p[11]);
    const unsigned b2 = pk2(p[12], p[13]), b3 = pk2(p[14], p[15]);
    const unsigned sa = hi ? a0 : a2;   // partner needs: hi0 sends a2 (k8,9->their w0)... 
    const unsigned sb = hi ? a1 : a3;   // (each lane sends what its partner lacks)
    const unsigned sc = hi ? b0 : b2;
    const unsigned sd = hi ? b1 : b3;
    const unsigned ta = (unsigned)__shfl_xor((int)sa, 32, 64);
    const unsigned tb = (unsigned)__shfl_xor((int)sb, 32, 64);
    const unsigned tc = (unsigned)__shfl_xor((int)sc, 32, 64);
    const unsigned td = (unsigned)__shfl_xor((int)sd, 32, 64);
    unsigned w[8];
    w[0] = hi ? ta : a0;
    w[1] = hi ? tb : a1;
    w[2] = hi ? a2 : ta;
    w[3] = hi ? a3 : tb;
    w[4] = hi ? tc : b0;
    w[5] = hi ? td : b1;
    w[6] = hi ? b2 : tc;
    w[7] = hi ? b3 : td;
    bf16x8 pf0, pf1;
    __builtin_memcpy(&pf0, &w[0], 16);
    __builtin_memcpy(&pf1, &w[4], 16);

    // O^T += V^T @ P^T : A-frag = vt row d, k-slice; B-frag = pf
#pragma unroll
    for (int ks = 0; ks < 2; ks++) {
      const bf16x8 pf = ks ? pf1 : pf0;
      const bf16x8 vf0 = *reinterpret_cast<const bf16x8*>(
          Vb + (size_t)(0 * 32 + ql) * SEQ + kv0 + ks * 16 + hi * 8);
      const bf16x8 vf1 = *reinterpret_cast<const bf16x8*>(
          Vb + (size_t)(1 * 32 + ql) * SEQ + kv0 + ks * 16 + hi * 8);
      oacc0 = __builtin_amdgcn_mfma_f32_32x32x16_bf16(vf0, pf, oacc0, 0, 0, 0);
      oacc1 = __builtin_amdgcn_mfma_f32_32x32x16_bf16(vf1, pf, oacc1, 0, 0, 0);
    }
  }

  const float inv = 1.0f / lrun;
  const size_t orow = ((size_t)b * SEQ + q0 + ql) * EMB + h * HD;
#pragma unroll
  for (int r = 0; r < 16; r++) {
    const int d = (r & 3) + 8 * (r >> 2) + 4 * hi;
    ob[orow + d]      = (bf16)(oacc0[r] * inv);
    ob[orow + 32 + d] = (bf16)(oacc1[r] * inv);
  }
}

extern "C" void kernel_launch(void* const* d_in, const int* in_sizes, int n_in,
                              void* d_out, int out_size, void* d_ws, size_t ws_size,
                              hipStream_t stream) {
  const float* x    = (const float*)d_in[0];   // query (reference only uses query)
  const float* Win  = (const float*)d_in[3];   // (3E, E)
  const float* bin  = (const float*)d_in[4];   // (3E,)
  const float* Wout = (const float*)d_in[5];   // (E, E)
  const float* bout = (const float*)d_in[6];   // (E,)
  float* out = (float*)d_out;

  char* p = (char*)d_ws;
  bf16* xb  = (bf16*)p; p += (size_t)MROWS * EMB * 2;       // 8 MB
  bf16* wb  = (bf16*)p; p += (size_t)3 * EMB * EMB * 2;     // 6 MB
  bf16* wob = (bf16*)p; p += (size_t)EMB * EMB * 2;         // 2 MB
  bf16* qb  = (bf16*)p; p += (size_t)MROWS * EMB * 2;       // 8 MB (B,H,S,D)
  bf16* kb  = (bf16*)p; p += (size_t)MROWS * EMB * 2;       // 8 MB (B,H,S,D)
  bf16* vt  = (bf16*)p; p += (size_t)MROWS * EMB * 2;       // 8 MB (B,H,D,S)
  bf16* ob  = (bf16*)p; p += (size_t)MROWS * EMB * 2;       // 8 MB (B,S,E)
  float* cosT = (float*)p; p += (size_t)SEQ * 32 * 4;
  float* sinT = (float*)p; p += (size_t)SEQ * 32 * 4;

  cvt_kernel<<<(MROWS * EMB / 4 + 255) / 256, 256, 0, stream>>>(x, xb, MROWS * EMB / 4);
  cvt_kernel<<<(3 * EMB * EMB / 4 + 255) / 256, 256, 0, stream>>>(Win, wb, 3 * EMB * EMB / 4);
  cvt_kernel<<<(EMB * EMB / 4 + 255) / 256, 256, 0, stream>>>(Wout, wob, EMB * EMB / 4);
  rope_tables_kernel<<<(SEQ * 32 + 255) / 256, 256, 0, stream>>>(cosT, sinT);

  gemm_bt<1><<<dim3(MROWS / 128, 3 * EMB / 128), 256, 0, stream>>>(
      xb, wb, bin, nullptr, qb, kb, vt, 3 * EMB, EMB);
  rope_apply_kernel<<<(BSZ * NH * SEQ * 32 + 255) / 256, 256, 0, stream>>>(qb, kb, cosT, sinT);
  attn_kernel<<<BSZ * NH * (SEQ / 128), 256, 0, stream>>>(qb, kb, vt, ob);
  gemm_bt<0><<<dim3(MROWS / 128, EMB / 128), 256, 0, stream>>>(
      ob, wob, bout, out, nullptr, nullptr, nullptr, EMB, EMB);
}